// Round 8
// baseline (125.514 us; speedup 1.0000x reference)
//
#include <hip/hip_runtime.h>

#define NN 10000
#define KK 64
#define CC 128
#define OUTOFF (NN * CC)
#define NA 256        // split-K blocks in kAR
#define CHUNKS_A 625  // 625 * 16 == 10000
#define NRED 128      // tail reducer blocks

// ws layout (floats): [0 .. NA*16384)   partials [b][m][k][c]  (16.8 MB)
//                     [UVW_OFF .. +16384)  UVW [m][k][c]
//                     [CNT_OFF .. +16)     done-counter
#define UVW_OFF ((size_t)NA * 16384)
#define CNT_OFF (UVW_OFF + 16384)

__device__ __forceinline__ float4 f4fma(float s, float4 v, float4 a) {
    a.x = fmaf(s, v.x, a.x); a.y = fmaf(s, v.y, a.y);
    a.z = fmaf(s, v.z, a.z); a.w = fmaf(s, v.w, a.w);
    return a;
}
__device__ __forceinline__ float4 f4add(float4 a, float4 b) {
    a.x += b.x; a.y += b.y; a.z += b.z; a.w += b.w; return a;
}

// ---------------- kAR: split-K partials (R0-proven body) + tail-block reduce + W-mult --------
__global__ __launch_bounds__(512) void kAR(const float* __restrict__ re,
                                           const float* __restrict__ im,
                                           const float* __restrict__ Qr,
                                           const float* __restrict__ Qi,
                                           const float* __restrict__ Ritz,
                                           const float* __restrict__ W,
                                           const int* __restrict__ ldp,
                                           float* __restrict__ ws)
{
    __shared__ float4 smem[1536];   // 24 KB: Qr 256 | Qi 256 | re 512 | im 512
    __shared__ int ticketS;
    const int t = threadIdx.x;
    const int bid = blockIdx.x;

    // ---- phase 1: split-K partial U,V (identical to R0 kA) ----
    {
        const int kt = t & 15;
        const int ctA = t >> 4;
        const int row_q = (t & 255) >> 4, q_q = t & 15;
        const int row_x = t >> 5,          q_x = t & 31;
        const float4* gq  = (const float4*)((t < 256) ? Qr : Qi);   // wave-uniform
        const float4* gre = (const float4*)re;
        const float4* gim = (const float4*)im;

        float aU[4][4] = {}, aV[4][4] = {};
        int cb = bid;
        float4 r0 = gq [(size_t)(cb * 16 + row_q) * 16 + q_q];
        float4 r1 = gre[(size_t)(cb * 16 + row_x) * 32 + q_x];
        float4 r2 = gim[(size_t)(cb * 16 + row_x) * 32 + q_x];

        while (true) {
            smem[t] = r0; smem[512 + t] = r1; smem[1024 + t] = r2;
            __syncthreads();
            const int nx = cb + NA;
            if (nx < CHUNKS_A) {
                const int m0 = nx * 16;
                r0 = gq [(size_t)(m0 + row_q) * 16 + q_q];
                r1 = gre[(size_t)(m0 + row_x) * 32 + q_x];
                r2 = gim[(size_t)(m0 + row_x) * 32 + q_x];
            }
#pragma unroll 4
            for (int rr = 0; rr < 16; ++rr) {
                float4 q_r = smem[rr * 16 + kt];
                float4 q_i = smem[256 + rr * 16 + kt];
                float4 x_r = smem[512 + rr * 32 + ctA];
                float4 x_i = smem[1024 + rr * 32 + ctA];
                float qr_[4] = {q_r.x, q_r.y, q_r.z, q_r.w};
                float qi_[4] = {q_i.x, q_i.y, q_i.z, q_i.w};
                float xr_[4] = {x_r.x, x_r.y, x_r.z, x_r.w};
                float xi_[4] = {x_i.x, x_i.y, x_i.z, x_i.w};
#pragma unroll
                for (int a = 0; a < 4; ++a)
#pragma unroll
                    for (int b = 0; b < 4; ++b) {
                        aU[a][b] = fmaf(qr_[a], xr_[b], aU[a][b]);
                        aU[a][b] = fmaf(qi_[a], xi_[b], aU[a][b]);
                        aV[a][b] = fmaf(qi_[a], xr_[b], aV[a][b]);
                        aV[a][b] = fmaf(-qr_[a], xi_[b], aV[a][b]);
                    }
            }
            __syncthreads();
            if (nx >= CHUNKS_A) break;
            cb = nx;
        }
        float* base = ws + (size_t)bid * 16384;
        const int k0 = kt * 4, c0 = ctA * 4;
#pragma unroll
        for (int a = 0; a < 4; ++a) {
            *(float4*)(base + (k0 + a) * CC + c0)        = make_float4(aU[a][0], aU[a][1], aU[a][2], aU[a][3]);
            *(float4*)(base + 8192 + (k0 + a) * CC + c0) = make_float4(aV[a][0], aV[a][1], aV[a][2], aV[a][3]);
        }
    }

    // ---- ticket: last NRED incrementers become reducers (R3-proven fence flow) ----
    unsigned* cnt = (unsigned*)(ws + CNT_OFF);
    __syncthreads();
    if (t == 0) {
        __threadfence();                 // release: this block's partials device-visible
        ticketS = (int)atomicAdd(cnt, 1u);
    }
    __syncthreads();
    const int ticket = ticketS;
    if (ticket < NA - NRED) return;      // block-uniform exit
    if (t == 0) {
        while (__hip_atomic_load(cnt, __ATOMIC_RELAXED, __HIP_MEMORY_SCOPE_AGENT) < NA)
            __builtin_amdgcn_s_sleep(2);
        __threadfence();                 // acquire: all partials visible
    }
    __syncthreads();

    // ---- phase 2: reduce 256 partials for (m,k), then UVW = TT * (row @ W) ----
    {
        const int role = ticket - (NA - NRED);   // 0..127
        const int m = role >> 6, k = role & 63;
        const int q = t & 31, sl = t >> 5;       // sl: 0..15 slices
        const float4* part4 = (const float4*)ws;
        const size_t base = (size_t)m * 2048 + k * 32 + q;
        const float4 z = make_float4(0.f, 0.f, 0.f, 0.f);
        float4 s0 = z, s1 = z, s2 = z, s3 = z;
#pragma unroll
        for (int jj = 0; jj < 4; ++jj) {         // 4 chains x 4 loads: b = sl + 16*(jj + 4*c)
            s0 = f4add(s0, part4[(size_t)(sl + 16 * (jj))      * 4096 + base]);
            s1 = f4add(s1, part4[(size_t)(sl + 16 * (jj + 4))  * 4096 + base]);
            s2 = f4add(s2, part4[(size_t)(sl + 16 * (jj + 8))  * 4096 + base]);
            s3 = f4add(s3, part4[(size_t)(sl + 16 * (jj + 12)) * 4096 + base]);
        }
        float4* red4 = smem;                     // 512 f4 reused
        float*  rowS = (float*)(smem + 512);     // 128 floats
        red4[t] = f4add(f4add(s0, s1), f4add(s2, s3));
        __syncthreads();
        if (t < 32) {
            float4 tot = z;
#pragma unroll
            for (int g = 0; g < 16; ++g) tot = f4add(tot, red4[g * 32 + t]);
            ((float4*)rowS)[t] = tot;
        }
        __syncthreads();
        if (t < 128) {
            float acc = 0.f;
#pragma unroll 8
            for (int cp = 0; cp < 128; ++cp)
                acc = fmaf(rowS[cp], W[cp * 128 + t], acc);
            const int ld = *ldp;
            const float rz = Ritz[k];
            float tt = 1.f;
            for (int i = 0; i < ld; ++i) tt *= rz;
            (ws + UVW_OFF)[m * 8192 + k * 128 + t] = tt * acc;
        }
    }
}

// ---------------- kC: res = Q @ UVW + masked-ReLU (R0 body, 32 rows/block, 4 waves/SIMD) ----
__global__ __launch_bounds__(512) void kC(const float* __restrict__ re,
                                          const float* __restrict__ im,
                                          const float* __restrict__ Qr,
                                          const float* __restrict__ Qi,
                                          const float* __restrict__ UVW,
                                          float* __restrict__ out)
{
    __shared__ float4 s[4096];   // 64 KB: [0..2047] UW [k][c4], [2048..4095] VW [k][c4]
    const int t = threadIdx.x;
    {
        const float4* g = (const float4*)UVW;
        for (int i = t; i < 4096; i += 512) s[i] = g[i];
    }
    __syncthreads();
    const int ct = t & 31;   // float4 col group
    const int r  = t >> 5;   // 0..15
    const int na = blockIdx.x * 32 + r;      // rows na and na+16; last block tail-guarded
    const int nb = na + 16;
    const bool bok = (nb < NN);
    const int nbs = bok ? nb : na;           // safe address for masked row

    const float4* qra = (const float4*)(Qr + (size_t)na * KK);
    const float4* qia = (const float4*)(Qi + (size_t)na * KK);
    const float4* qrb = (const float4*)(Qr + (size_t)nbs * KK);
    const float4* qib = (const float4*)(Qi + (size_t)nbs * KK);

    float4 z = make_float4(0.f, 0.f, 0.f, 0.f);
    float4 Ra = z, Ia = z, Rb = z, Ib = z;

#pragma unroll 4
    for (int k4 = 0; k4 < 16; ++k4) {
        float4 QRa = qra[k4], QIa = qia[k4];
        float4 QRb = qrb[k4], QIb = qib[k4];
        float ar[4] = {QRa.x, QRa.y, QRa.z, QRa.w};
        float ai[4] = {QIa.x, QIa.y, QIa.z, QIa.w};
        float br[4] = {QRb.x, QRb.y, QRb.z, QRb.w};
        float bi[4] = {QIb.x, QIb.y, QIb.z, QIb.w};
#pragma unroll
        for (int jj = 0; jj < 4; ++jj) {
            const int k = k4 * 4 + jj;
            float4 uw = s[k * 32 + ct];
            float4 vw = s[2048 + k * 32 + ct];
            Ra = f4fma(ar[jj], uw, Ra); Ra = f4fma(ai[jj], vw, Ra);
            Ia = f4fma(ai[jj], uw, Ia); Ia = f4fma(-ar[jj], vw, Ia);
            Rb = f4fma(br[jj], uw, Rb); Rb = f4fma(bi[jj], vw, Rb);
            Ib = f4fma(bi[jj], uw, Ib); Ib = f4fma(-br[jj], vw, Ib);
        }
    }
    const int cc = ct * 4;
    {
        float4 rin = *(const float4*)(re + (size_t)na * CC + cc);
        float4 iin = *(const float4*)(im + (size_t)na * CC + cc);
        float4 orr, oii;
        orr.x = rin.x + (Ra.x >= 0.f ? Ra.x : 0.f); oii.x = iin.x + (Ra.x >= 0.f ? Ia.x : 0.f);
        orr.y = rin.y + (Ra.y >= 0.f ? Ra.y : 0.f); oii.y = iin.y + (Ra.y >= 0.f ? Ia.y : 0.f);
        orr.z = rin.z + (Ra.z >= 0.f ? Ra.z : 0.f); oii.z = iin.z + (Ra.z >= 0.f ? Ia.z : 0.f);
        orr.w = rin.w + (Ra.w >= 0.f ? Ra.w : 0.f); oii.w = iin.w + (Ra.w >= 0.f ? Ia.w : 0.f);
        *(float4*)(out + (size_t)na * CC + cc)          = orr;
        *(float4*)(out + OUTOFF + (size_t)na * CC + cc) = oii;
    }
    if (bok) {
        float4 rin = *(const float4*)(re + (size_t)nb * CC + cc);
        float4 iin = *(const float4*)(im + (size_t)nb * CC + cc);
        float4 orr, oii;
        orr.x = rin.x + (Rb.x >= 0.f ? Rb.x : 0.f); oii.x = iin.x + (Rb.x >= 0.f ? Ib.x : 0.f);
        orr.y = rin.y + (Rb.y >= 0.f ? Rb.y : 0.f); oii.y = iin.y + (Rb.y >= 0.f ? Ib.y : 0.f);
        orr.z = rin.z + (Rb.z >= 0.f ? Rb.z : 0.f); oii.z = iin.z + (Rb.z >= 0.f ? Ib.z : 0.f);
        orr.w = rin.w + (Rb.w >= 0.f ? Rb.w : 0.f); oii.w = iin.w + (Rb.w >= 0.f ? Ib.w : 0.f);
        *(float4*)(out + (size_t)nb * CC + cc)          = orr;
        *(float4*)(out + OUTOFF + (size_t)nb * CC + cc) = oii;
    }
}

extern "C" void kernel_launch(void* const* d_in, const int* in_sizes, int n_in,
                              void* d_out, int out_size, void* d_ws, size_t ws_size,
                              hipStream_t stream) {
    const float* re   = (const float*)d_in[0];
    const float* im   = (const float*)d_in[1];
    const float* Qr   = (const float*)d_in[2];
    const float* Qi   = (const float*)d_in[3];
    const float* Ritz = (const float*)d_in[4];
    const float* W    = (const float*)d_in[5];
    const int*   ldp  = (const int*)d_in[6];
    float* out = (float*)d_out;
    float* ws  = (float*)d_ws;

    hipMemsetAsync(ws + CNT_OFF, 0, 64, stream);   // zero done-counter (ws is poisoned)
    kAR<<<NA, 512, 0, stream>>>(re, im, Qr, Qi, Ritz, W, ldp, ws);
    kC <<<313, 512, 0, stream>>>(re, im, Qr, Qi, ws + UVW_OFF, out);
}